// Round 19
// baseline (165.305 us; speedup 1.0000x reference)
//
#include <hip/hip_runtime.h>

#define SHIFT 4

typedef __bf16 bf16x8 __attribute__((ext_vector_type(8)));
typedef __bf16 bf16x4 __attribute__((ext_vector_type(4)));
typedef float  f32x4  __attribute__((ext_vector_type(4)));

// Swizzled 96-stride regions (h, k, w1c): elem = (row*96+col) ^ ((row&7)<<3).
#define SWZ(row, col) ((((row) * 96) + (col)) ^ (((row) & 7) << 3))

// Linear LDS strides.
#define LDV 72    // v transposed rows  (36 dw % 32 = 4 -> 2-way, free)
#define LDU 72    // u rows (MLP)
#define LDW2 72   // w2 chunk rows: [96 outcols][64 j]

// ws layout (bf16 elements unless noted):
//   frag region @ 0     : 72 frags x 512 (qkv c*18+t*3+ks: 0..53; proj 54+t*3+ks)
//   w1T         @ 36864 : [384 outcols][96 k]
//   w2C         @ 73728 : [6 chunks][96 outcols][64 j]
//   bias_v f32  @ byte 221184 : [4 variants][3][64 q][64 ktok], x log2e, mask folded
#define WS_W1T  36864
#define WS_W2C  73728
#define WS_BIAS_BYTES 221184
#define LOG2E 1.4426950408889634f

// ---------------------------------------------------------------------------
// Kernel 0: weight prep + 4-variant masked bias tensor.
// ---------------------------------------------------------------------------
__global__ __launch_bounds__(256)
void swin_prep_kernel(const float* __restrict__ qkvw, const float* __restrict__ projw,
                      const float* __restrict__ w1, const float* __restrict__ w2,
                      const float* __restrict__ btab,
                      __bf16* __restrict__ ws)
{
  const int i = blockIdx.x * 256 + threadIdx.x;
  if (i < 36864) {                       // fragment-ordered qkv + proj
    const int fi = i >> 9, e = i & 511;
    const int lane = e >> 3, j = e & 7;
    const int l15 = lane & 15;
    const int kk  = (lane >> 4) * 8 + j;
    float v;
    if (fi < 54) {                       // qkvw [96][288]
      const int c = fi / 18, rem = fi % 18, t = rem / 3, ks = rem % 3;
      v = qkvw[(ks * 32 + kk) * 288 + c * 96 + t * 16 + l15];
    } else {                             // projw [96][96]
      const int f2 = fi - 54, t = f2 / 3, ks = f2 % 3;
      v = projw[(ks * 32 + kk) * 96 + t * 16 + l15];
    }
    ws[i] = (__bf16)v;
  } else if (i < 73728) {                // w1T [384][96]; w1 is [96][384]
    const int j = i - WS_W1T;
    const int col = j / 96, kk = j - col * 96;
    ws[i] = (__bf16)w1[kk * 384 + col];
  } else if (i < 110592) {               // w2C [6][96][64]; w2 is [384][96]
    const int j = i - WS_W2C;
    const int cc = j / 6144, r2 = j - cc * 6144;
    const int o = r2 / 64, jl = r2 - o * 64;
    ws[i] = (__bf16)w2[(cc * 64 + jl) * 96 + o];
  } else if (i < 159744) {               // bias_v[variant][h][q][ktok]
    const int jj = i - 110592;           // < 49152
    const int m = jj & 63, n = (jj >> 6) & 63;   // n=q row, m=ktok col
    const int hv = jj >> 12;             // 0..11
    const int h = hv % 3, variant = hv / 3;
    const int vy = variant >> 1, vx = variant & 1;
    const int ti = n >> 3, tj = n & 7, ki = m >> 3, kj = m & 7;
    const int ryn = vy ? (ti < 4 ? 1 : 2) : 0;
    const int rxn = vx ? (tj < 4 ? 1 : 2) : 0;
    const int rym = vy ? (ki < 4 ? 1 : 2) : 0;
    const int rxm = vx ? (kj < 4 ? 1 : 2) : 0;
    const float mk = (ryn == rym && rxn == rxm) ? 0.f : -100.f;
    const float bv = btab[(((ti - ki) + 7) * 15 + ((tj - kj) + 7)) * 3 + h];
    float* biasf = (float*)((char*)ws + WS_BIAS_BYTES);
    biasf[jj] = (bv + mk) * LOG2E;
  }
}

// ---------------------------------------------------------------------------
// Fused kernel. R19: attention split into phase-A (ALL heads QK+softmax in
// registers, cross-head ILP) and phase-B (per-head P->LDS->PV, the only
// serial part). Otherwise R18 (swizzled h/k/w1 regions, 38400 B LDS).
// ---------------------------------------------------------------------------
__global__ __launch_bounds__(256, 4)
void swin_block_kernel(const float* __restrict__ x,
                       const float* __restrict__ ln1g, const float* __restrict__ ln1b,
                       const __bf16* __restrict__ ws, const float* __restrict__ qkvb,
                       const float* __restrict__ ln2g, const float* __restrict__ ln2b,
                       float* __restrict__ out)
{
  __shared__ __align__(16) char lds[38400];
  __bf16* h_s = (__bf16*)lds;              // [64][96] swz  12288 B
  __bf16* k_s = (__bf16*)(lds + 12288);    // [64][96] swz  12288 B
  __bf16* v_s = (__bf16*)(lds + 24576);    // [3][32][LDV]  13824 B
  // MLP-phase aliases:
  __bf16* w1c = (__bf16*)(lds + 12288);    // [64][96] swz
  __bf16* u_c = (__bf16*)(lds + 12288);    // [64][LDU] linear (over w1c after bar)
  __bf16* w2c = (__bf16*)(lds + 24576);    // [96][LDW2] linear

  const float* biasf = (const float*)((const char*)ws + WS_BIAS_BYTES);

  const int tid  = threadIdx.x;
  const int lane = tid & 63;
  const int wv   = tid >> 6;
  const int l15  = lane & 15;
  const int g4   = lane >> 4;
  const int blk  = blockIdx.x;          // b*256 + wy*16 + wx
  const int b    = blk >> 8;
  const int wy   = (blk >> 4) & 15;
  const int wx   = blk & 15;

  // ---------------- Phase 1: LayerNorm1 ----------------
  {
    const int t = tid >> 2, p = tid & 3;
    const int ti = t >> 3, tj = t & 7;
    const int iy = (wy * 8 + ti + SHIFT) & 127;
    const int ix = (wx * 8 + tj + SHIFT) & 127;
    const float* rowp = x + ((size_t)(b * 16384 + iy * 128 + ix)) * 96 + p * 24;
    float vb[24];
    float s = 0.f, ss = 0.f;
#pragma unroll
    for (int u = 0; u < 6; ++u) {
      f32x4 f = *(const f32x4*)(rowp + 4 * u);
#pragma unroll
      for (int e = 0; e < 4; ++e) { float q = f[e]; vb[4*u+e] = q; s += q; ss += q*q; }
    }
    s  += __shfl_xor(s, 1);  s  += __shfl_xor(s, 2);
    ss += __shfl_xor(ss, 1); ss += __shfl_xor(ss, 2);
    const float mean = s * (1.f / 96.f);
    const float var  = ss * (1.f / 96.f) - mean * mean;
    const float rstd = rsqrtf(var + 1e-5f);
#pragma unroll
    for (int u = 0; u < 6; ++u) {
      f32x4 gg = *(const f32x4*)(ln1g + p * 24 + 4 * u);
      f32x4 bb = *(const f32x4*)(ln1b + p * 24 + 4 * u);
      f32x4 nv;
#pragma unroll
      for (int e = 0; e < 4; ++e) nv[e] = (vb[4*u+e] - mean) * rstd * gg[e] + bb[e];
      *(bf16x4*)&h_s[SWZ(t, p * 24 + 4 * u)] = __builtin_convertvector(nv, bf16x4);
    }
  }
  // no barrier: phase 2 reads only own-wave h rows

  // ---------------- Phase 2: QKV projection ----------------
  const float qscale = 0.17677669529663687f * LOG2E;
  const __bf16* fbase = ws + (size_t)lane * 8;
  const int rowb = 16 * wv;
  bf16x8 aq3[3];
#pragma unroll
  for (int c = 0; c < 3; ++c) {
    bf16x8 wf[6][3];
#pragma unroll
    for (int t = 0; t < 6; ++t)
#pragma unroll
      for (int ks = 0; ks < 3; ++ks)
        wf[t][ks] = *(const bf16x8*)(fbase + (size_t)(c * 18 + t * 3 + ks) * 512);
    f32x4 acc[6];
#pragma unroll
    for (int t = 0; t < 6; ++t) {
      const float bv = qkvb[c * 96 + t * 16 + l15];
      f32x4 a4 = {bv, bv, bv, bv};
      acc[t] = a4;
    }
#pragma unroll
    for (int ks = 0; ks < 3; ++ks) {
      bf16x8 a = *(const bf16x8*)&h_s[SWZ(rowb + l15, ks * 32 + 8 * g4)];
#pragma unroll
      for (int t = 0; t < 6; ++t)
        acc[t] = __builtin_amdgcn_mfma_f32_16x16x32_bf16(a, wf[t][ks], acc[t], 0, 0, 0);
    }
    if (c == 0) {
#pragma unroll
      for (int t = 0; t < 6; ++t) {
        const int col = (t >> 1) * 32 + (t & 1) * 16 + l15;
#pragma unroll
        for (int r = 0; r < 4; ++r)
          k_s[SWZ(rowb + 4 * g4 + r, col)] = (__bf16)(acc[t][r] * qscale);
      }
#pragma unroll
      for (int h = 0; h < 3; ++h)
        aq3[h] = *(const bf16x8*)&k_s[SWZ(rowb + l15, h * 32 + 8 * g4)];
    } else if (c == 1) {
#pragma unroll
      for (int t = 0; t < 6; ++t) {
        const int col = (t >> 1) * 32 + (t & 1) * 16 + l15;
#pragma unroll
        for (int r = 0; r < 4; ++r)
          k_s[SWZ(rowb + 4 * g4 + r, col)] = (__bf16)acc[t][r];
      }
    } else {
#pragma unroll
      for (int t = 0; t < 6; ++t) {
        const int head = t >> 1, dim = (t & 1) * 16 + l15;
        *(bf16x4*)&v_s[(head * 32 + dim) * LDV + rowb + 4 * g4] =
            __builtin_convertvector(acc[t], bf16x4);
      }
    }
  }

  __syncthreads();   // barrier #1: k_s/v_s visible; h region dead

  // ---------------- Phase 3A: ALL heads QK + softmax (registers only) -------
  const float* bvar = biasf + (((wy == 15) * 2 + (wx == 15)) * 3) * 4096;
  const f32x4 zf = {0.f, 0.f, 0.f, 0.f};
  f32x4 p3[3][4];
  float rs3[3];
#pragma unroll
  for (int h = 0; h < 3; ++h) {
    const float* bh = bvar + h * 4096;
    f32x4 bv[4];
#pragma unroll
    for (int n = 0; n < 4; ++n)
      bv[n] = *(const f32x4*)&bh[(rowb + l15) * 64 + n * 16 + 4 * g4];
#pragma unroll
    for (int n = 0; n < 4; ++n) {
      bf16x8 bk = *(const bf16x8*)&k_s[SWZ(n * 16 + l15, h * 32 + 8 * g4)];
      p3[h][n] = __builtin_amdgcn_mfma_f32_16x16x32_bf16(bk, aq3[h], zf, 0, 0, 0);
    }
    float sum = 0.f;
#pragma unroll
    for (int n = 0; n < 4; ++n)
#pragma unroll
      for (int r = 0; r < 4; ++r) {
        const float p = __builtin_amdgcn_exp2f(p3[h][n][r] + bv[n][r]);
        p3[h][n][r] = p; sum += p;
      }
    sum += __shfl_xor(sum, 16); sum += __shfl_xor(sum, 32);
    rs3[h] = __builtin_amdgcn_rcpf(sum);
  }

  // ---------------- Phase 3B: per-head P->LDS->PV (serial via shared P) -----
  f32x4 ovA[3][2];
#pragma unroll
  for (int h = 0; h < 3; ++h) {
#pragma unroll
    for (int n = 0; n < 4; ++n) {
      f32x4 pn;
#pragma unroll
      for (int r = 0; r < 4; ++r) pn[r] = p3[h][n][r] * rs3[h];
      *(bf16x4*)&h_s[SWZ(rowb + l15, n * 16 + 4 * g4)] =
          __builtin_convertvector(pn, bf16x4);
    }
    f32x4 ov[2] = {zf, zf};
#pragma unroll
    for (int ks = 0; ks < 2; ++ks) {
      bf16x8 pa = *(const bf16x8*)&h_s[SWZ(rowb + l15, ks * 32 + 8 * g4)];
#pragma unroll
      for (int t2 = 0; t2 < 2; ++t2) {
        bf16x8 vb2 = *(const bf16x8*)&v_s[(h * 32 + t2 * 16 + l15) * LDV + ks * 32 + 8 * g4];
        ov[t2] = __builtin_amdgcn_mfma_f32_16x16x32_bf16(pa, vb2, ov[t2], 0, 0, 0);
      }
    }
    ovA[h][0] = ov[0];
    ovA[h][1] = ov[1];
  }
  // flush attn-out to h_s (overwrites dead P; wave-local rows)
#pragma unroll
  for (int h = 0; h < 3; ++h)
#pragma unroll
    for (int t2 = 0; t2 < 2; ++t2)
#pragma unroll
      for (int r = 0; r < 4; ++r)
        h_s[SWZ(rowb + 4 * g4 + r, h * 32 + t2 * 16 + l15)] = (__bf16)ovA[h][t2][r];
  // no barrier: proj reads only own-wave rows

  // ---------------- Phase 4: output projection ----------------
  f32x4 po[6];
#pragma unroll
  for (int t = 0; t < 6; ++t) po[t] = zf;
#pragma unroll
  for (int ks = 0; ks < 3; ++ks) {
    bf16x8 a = *(const bf16x8*)&h_s[SWZ(rowb + l15, ks * 32 + 8 * g4)];
#pragma unroll
    for (int t = 0; t < 6; ++t) {
      bf16x8 bb = *(const bf16x8*)(fbase + (size_t)(54 + t * 3 + ks) * 512);
      po[t] = __builtin_amdgcn_mfma_f32_16x16x32_bf16(a, bb, po[t], 0, 0, 0);
    }
  }

  // ---------------- Phase 4.5: residual + LN2 in registers ----------------
  size_t gbase[4];
  float xm[6][4];
#pragma unroll
  for (int r = 0; r < 4; ++r) {
    const int row = rowb + 4 * g4 + r;
    const int ti2 = row >> 3, tj2 = row & 7;
    const int iy = (wy * 8 + ti2 + SHIFT) & 127;
    const int ix = (wx * 8 + tj2 + SHIFT) & 127;
    gbase[r] = ((size_t)(b * 16384 + iy * 128 + ix)) * 96;
#pragma unroll
    for (int t = 0; t < 6; ++t)
      xm[t][r] = x[gbase[r] + t * 16 + l15] + po[t][r];
  }
  {
    float g6[6], b6[6];
#pragma unroll
    for (int t = 0; t < 6; ++t) { g6[t] = ln2g[t * 16 + l15]; b6[t] = ln2b[t * 16 + l15]; }
#pragma unroll
    for (int r = 0; r < 4; ++r) {
      float s = 0.f, ss = 0.f;
#pragma unroll
      for (int t = 0; t < 6; ++t) { s += xm[t][r]; ss += xm[t][r] * xm[t][r]; }
      s  += __shfl_xor(s, 1);  s  += __shfl_xor(s, 2);
      s  += __shfl_xor(s, 4);  s  += __shfl_xor(s, 8);
      ss += __shfl_xor(ss, 1); ss += __shfl_xor(ss, 2);
      ss += __shfl_xor(ss, 4); ss += __shfl_xor(ss, 8);
      const float mean = s * (1.f / 96.f);
      const float var  = ss * (1.f / 96.f) - mean * mean;
      const float rstd = rsqrtf(var + 1e-5f);
#pragma unroll
      for (int t = 0; t < 6; ++t) {
        const float h2 = (xm[t][r] - mean) * rstd * g6[t] + b6[t];
        h_s[SWZ(rowb + 4 * g4 + r, t * 16 + l15)] = (__bf16)h2;
      }
    }
  }

  __syncthreads();   // barrier #2: k/v regions reusable

  // ---------------- Phase 5: MLP, 6 chunks of 64 hidden cols ----------------
  f32x4 acc[6];
#pragma unroll
  for (int t = 0; t < 6; ++t) acc[t] = zf;

  for (int cc = 0; cc < 6; ++cc) {
    {  // stage both chunks in one exposure
      const __bf16* s1 = ws + WS_W1T + cc * 6144;
#pragma unroll
      for (int m = tid; m < 768; m += 256) {
        const int row = m / 12, q4 = m - row * 12;
        *(uint4*)&w1c[SWZ(row, q4 * 8)] = *(const uint4*)&s1[row * 96 + q4 * 8];
      }
      const __bf16* s2 = ws + WS_W2C + cc * 6144;
#pragma unroll
      for (int m = tid; m < 768; m += 256) {
        const int row = m >> 3, q4 = m & 7;
        *(uint4*)&w2c[row * LDW2 + q4 * 8] = *(const uint4*)&s2[row * 64 + q4 * 8];
      }
    }
    __syncthreads();
    f32x4 ua[4];
#pragma unroll
    for (int t = 0; t < 4; ++t) ua[t] = zf;
#pragma unroll
    for (int ks = 0; ks < 3; ++ks) {
      bf16x8 a = *(const bf16x8*)&h_s[SWZ(rowb + l15, ks * 32 + 8 * g4)];
#pragma unroll
      for (int t = 0; t < 4; ++t) {
        bf16x8 bb = *(const bf16x8*)&w1c[SWZ(t * 16 + l15, ks * 32 + 8 * g4)];
        ua[t] = __builtin_amdgcn_mfma_f32_16x16x32_bf16(a, bb, ua[t], 0, 0, 0);
      }
    }
    __syncthreads();   // w1c reads done -> region reusable as u
#pragma unroll
    for (int t = 0; t < 4; ++t)
#pragma unroll
      for (int r = 0; r < 4; ++r) {
        const float v = ua[t][r];
        const float e = __builtin_amdgcn_exp2f(2.3022528717f * (v + 0.044715f * v * v * v));
        const float g = v - v * __builtin_amdgcn_rcpf(e + 1.f);
        u_c[(rowb + 4 * g4 + r) * LDU + t * 16 + l15] = (__bf16)g;
      }
#pragma unroll
    for (int ks = 0; ks < 2; ++ks) {
      bf16x8 pa = *(const bf16x8*)&u_c[(rowb + l15) * LDU + ks * 32 + 8 * g4];
#pragma unroll
      for (int t = 0; t < 6; ++t) {
        bf16x8 bb = *(const bf16x8*)&w2c[(t * 16 + l15) * LDW2 + ks * 32 + 8 * g4];
        acc[t] = __builtin_amdgcn_mfma_f32_16x16x32_bf16(pa, bb, acc[t], 0, 0, 0);
      }
    }
    __syncthreads();   // w2c/u reads done -> restageable
  }

  // ---------------- Epilogue: out = x_mid + mlp ----------------
#pragma unroll
  for (int r = 0; r < 4; ++r)
#pragma unroll
    for (int t = 0; t < 6; ++t)
      out[gbase[r] + t * 16 + l15] = xm[t][r] + acc[t][r];
}

extern "C" void kernel_launch(void* const* d_in, const int* in_sizes, int n_in,
                              void* d_out, int out_size, void* d_ws, size_t ws_size,
                              hipStream_t stream) {
  (void)in_sizes; (void)n_in; (void)out_size; (void)ws_size;
  const float* x     = (const float*)d_in[0];
  const float* ln1g  = (const float*)d_in[1];
  const float* ln1b  = (const float*)d_in[2];
  const float* qkvw  = (const float*)d_in[3];
  const float* qkvb  = (const float*)d_in[4];
  const float* projw = (const float*)d_in[5];
  const float* btab  = (const float*)d_in[6];
  const float* ln2g  = (const float*)d_in[7];
  const float* ln2b  = (const float*)d_in[8];
  const float* w1    = (const float*)d_in[9];
  const float* w2    = (const float*)d_in[10];
  float* out = (float*)d_out;
  __bf16* ws = (__bf16*)d_ws;

  // 159744 items = 110592 weight elems + 49152 bias elems (4 variants)
  swin_prep_kernel<<<624, 256, 0, stream>>>(qkvw, projw, w1, w2, btab, ws);
  swin_block_kernel<<<4096, 256, 0, stream>>>(x, ln1g, ln1b, ws, qkvb, ln2g, ln2b, out);
}

// Round 20
// 158.449 us; speedup vs baseline: 1.0433x; 1.0433x over previous
//
#include <hip/hip_runtime.h>

#define SHIFT 4

typedef __bf16 bf16x8 __attribute__((ext_vector_type(8)));
typedef __bf16 bf16x4 __attribute__((ext_vector_type(4)));
typedef float  f32x4  __attribute__((ext_vector_type(4)));

// LDS leading dims (elements).
#define LDA 104   // h rows (and packed k rows)
#define LDV 72    // v transposed rows
#define LDU 72    // u rows (MLP, 64 cols used)
#define LDW1 104  // w1 chunk rows: [64 outcols][96 k]
#define LDW2 72   // w2 chunk rows: [96 outcols][64 j]

// ws layout (bf16 elements unless noted):
//   frag region @ 0     : 72 frags x 512 (qkv c*18+t*3+ks: 0..53; proj 54+t*3+ks)
//   w1T         @ 36864 : [384 outcols][96 k]      (64-row chunks contiguous)
//   w2C         @ 73728 : [6 chunks][96 outcols][64 j]
//   bias_v f32  @ byte 221184 : [4 variants][3][64 q][64 ktok]
//     variant = (wy==15)*2 + (wx==15); value = (relpos_bias + shift_mask)*log2e
#define WS_W1T  36864
#define WS_W2C  73728
#define WS_BIAS_BYTES 221184
#define LOG2E 1.4426950408889634f

// ---------------------------------------------------------------------------
// Kernel 0: weight prep + 4-variant masked bias tensor (mask folded, x log2e).
// ---------------------------------------------------------------------------
__global__ __launch_bounds__(256)
void swin_prep_kernel(const float* __restrict__ qkvw, const float* __restrict__ projw,
                      const float* __restrict__ w1, const float* __restrict__ w2,
                      const float* __restrict__ btab,
                      __bf16* __restrict__ ws)
{
  const int i = blockIdx.x * 256 + threadIdx.x;
  if (i < 36864) {                       // fragment-ordered qkv + proj
    const int fi = i >> 9, e = i & 511;
    const int lane = e >> 3, j = e & 7;
    const int l15 = lane & 15;
    const int kk  = (lane >> 4) * 8 + j;
    float v;
    if (fi < 54) {                       // qkvw [96][288]
      const int c = fi / 18, rem = fi % 18, t = rem / 3, ks = rem % 3;
      v = qkvw[(ks * 32 + kk) * 288 + c * 96 + t * 16 + l15];
    } else {                             // projw [96][96]
      const int f2 = fi - 54, t = f2 / 3, ks = f2 % 3;
      v = projw[(ks * 32 + kk) * 96 + t * 16 + l15];
    }
    ws[i] = (__bf16)v;
  } else if (i < 73728) {                // w1T [384][96]; w1 is [96][384]
    const int j = i - WS_W1T;
    const int col = j / 96, kk = j - col * 96;
    ws[i] = (__bf16)w1[kk * 384 + col];
  } else if (i < 110592) {               // w2C [6][96][64]; w2 is [384][96]
    const int j = i - WS_W2C;
    const int cc = j / 6144, r2 = j - cc * 6144;
    const int o = r2 / 64, jl = r2 - o * 64;
    ws[i] = (__bf16)w2[(cc * 64 + jl) * 96 + o];
  } else if (i < 159744) {               // bias_v[variant][h][q][ktok]
    const int jj = i - 110592;           // < 49152
    const int m = jj & 63, n = (jj >> 6) & 63;   // n=q row, m=ktok col
    const int hv = jj >> 12;             // 0..11
    const int h = hv % 3, variant = hv / 3;
    const int vy = variant >> 1, vx = variant & 1;
    const int ti = n >> 3, tj = n & 7, ki = m >> 3, kj = m & 7;
    const int ryn = vy ? (ti < 4 ? 1 : 2) : 0;
    const int rxn = vx ? (tj < 4 ? 1 : 2) : 0;
    const int rym = vy ? (ki < 4 ? 1 : 2) : 0;
    const int rxm = vx ? (kj < 4 ? 1 : 2) : 0;
    const float mk = (ryn == rym && rxn == rxm) ? 0.f : -100.f;
    const float bv = btab[(((ti - ki) + 7) * 15 + ((tj - kj) + 7)) * 3 + h];
    float* biasf = (float*)((char*)ws + WS_BIAS_BYTES);
    biasf[jj] = (bv + mk) * LOG2E;
  }
}

// ---------------------------------------------------------------------------
// Fused kernel: LN1 + shift/partition + MHSA + proj + residual + LN2 (regs)
// + MLP + residual. One block per 8x8 window, 4 waves; wave wv owns rows
// 16wv..16wv+15 end-to-end. LDS 40448 B -> 4 blocks/CU.
// R20 = R17 (best measured): swapped QK^T in-lane softmax, masked-bias table,
// HW exp2, single-exposure MLP staging. (R18 swizzle: conflicts -35% but time
// within noise; R19 register-softmax: spilled, reverted.)
// ---------------------------------------------------------------------------
__global__ __launch_bounds__(256, 4)
void swin_block_kernel(const float* __restrict__ x,
                       const float* __restrict__ ln1g, const float* __restrict__ ln1b,
                       const __bf16* __restrict__ ws, const float* __restrict__ qkvb,
                       const float* __restrict__ ln2g, const float* __restrict__ ln2b,
                       float* __restrict__ out)
{
  __shared__ __align__(16) char lds[40448];
  __bf16* h_s = (__bf16*)lds;              // [64][LDA]    13312 B (h, P, attn-out, h2)
  __bf16* k_s = (__bf16*)(lds + 13312);    // [64][LDA]    13312 B (q-scratch, then k)
  __bf16* v_s = (__bf16*)(lds + 26624);    // [3][32][LDV] 13824 B
  // MLP-phase aliases (k/v dead after attention):
  __bf16* w1c = (__bf16*)(lds + 13312);    // [64][LDW1] 13312 B (k-region)
  __bf16* u_c = (__bf16*)(lds + 13312);    // [64][LDU]   9216 B (over w1c after bar)
  __bf16* w2c = (__bf16*)(lds + 26624);    // [96][LDW2] 13824 B (v-region)

  const float* biasf = (const float*)((const char*)ws + WS_BIAS_BYTES);

  const int tid  = threadIdx.x;
  const int lane = tid & 63;
  const int wv   = tid >> 6;
  const int l15  = lane & 15;
  const int g4   = lane >> 4;
  const int blk  = blockIdx.x;          // b*256 + wy*16 + wx
  const int b    = blk >> 8;
  const int wy   = (blk >> 4) & 15;
  const int wx   = blk & 15;

  // ---------------- Phase 1: LayerNorm1 (4 lanes/token; wave-local rows) ----
  {
    const int t = tid >> 2, p = tid & 3;
    const int ti = t >> 3, tj = t & 7;
    const int iy = (wy * 8 + ti + SHIFT) & 127;
    const int ix = (wx * 8 + tj + SHIFT) & 127;
    const float* rowp = x + ((size_t)(b * 16384 + iy * 128 + ix)) * 96 + p * 24;
    float vb[24];
    float s = 0.f, ss = 0.f;
#pragma unroll
    for (int u = 0; u < 6; ++u) {
      f32x4 f = *(const f32x4*)(rowp + 4 * u);
#pragma unroll
      for (int e = 0; e < 4; ++e) { float q = f[e]; vb[4*u+e] = q; s += q; ss += q*q; }
    }
    s  += __shfl_xor(s, 1);  s  += __shfl_xor(s, 2);
    ss += __shfl_xor(ss, 1); ss += __shfl_xor(ss, 2);
    const float mean = s * (1.f / 96.f);
    const float var  = ss * (1.f / 96.f) - mean * mean;
    const float rstd = rsqrtf(var + 1e-5f);
#pragma unroll
    for (int u = 0; u < 6; ++u) {
      f32x4 gg = *(const f32x4*)(ln1g + p * 24 + 4 * u);
      f32x4 bb = *(const f32x4*)(ln1b + p * 24 + 4 * u);
      f32x4 nv;
#pragma unroll
      for (int e = 0; e < 4; ++e) nv[e] = (vb[4*u+e] - mean) * rstd * gg[e] + bb[e];
      *(bf16x4*)&h_s[t * LDA + p * 24 + 4 * u] = __builtin_convertvector(nv, bf16x4);
    }
  }
  // no barrier: phase 2 reads only own-wave h rows

  // ---------------- Phase 2: QKV projection (B-frags direct from global) ----
  const float qscale = 0.17677669529663687f * LOG2E;  // 1/sqrt(32) * log2e fold
  const __bf16* fbase = ws + (size_t)lane * 8;
  const int rowb = 16 * wv;
  bf16x8 aq3[3];
#pragma unroll
  for (int c = 0; c < 3; ++c) {
    bf16x8 wf[6][3];
#pragma unroll
    for (int t = 0; t < 6; ++t)
#pragma unroll
      for (int ks = 0; ks < 3; ++ks)
        wf[t][ks] = *(const bf16x8*)(fbase + (size_t)(c * 18 + t * 3 + ks) * 512);
    f32x4 acc[6];
#pragma unroll
    for (int t = 0; t < 6; ++t) {
      const float bv = qkvb[c * 96 + t * 16 + l15];
      f32x4 a4 = {bv, bv, bv, bv};
      acc[t] = a4;
    }
#pragma unroll
    for (int ks = 0; ks < 3; ++ks) {
      bf16x8 a = *(const bf16x8*)&h_s[(rowb + l15) * LDA + ks * 32 + 8 * g4];
#pragma unroll
      for (int t = 0; t < 6; ++t)
        acc[t] = __builtin_amdgcn_mfma_f32_16x16x32_bf16(a, wf[t][ks], acc[t], 0, 0, 0);
    }
    if (c == 0) {
      // q: scatter into k_s as scratch (own rows), read back A-frags; c==1's
      // k scatter overwrites same own rows -> no cross-wave race.
#pragma unroll
      for (int t = 0; t < 6; ++t) {
        const int col = (t >> 1) * 32 + (t & 1) * 16 + l15;   // head*32 + dim
#pragma unroll
        for (int r = 0; r < 4; ++r)
          k_s[(rowb + 4 * g4 + r) * LDA + col] = (__bf16)(acc[t][r] * qscale);
      }
#pragma unroll
      for (int h = 0; h < 3; ++h)
        aq3[h] = *(const bf16x8*)&k_s[(rowb + l15) * LDA + h * 32 + 8 * g4];
    } else if (c == 1) {
#pragma unroll
      for (int t = 0; t < 6; ++t) {
        const int col = (t >> 1) * 32 + (t & 1) * 16 + l15;
#pragma unroll
        for (int r = 0; r < 4; ++r)
          k_s[(rowb + 4 * g4 + r) * LDA + col] = (__bf16)acc[t][r];
      }
    } else {  // v transposed [head][dim][tok]; 4 regs = 4 consecutive toks
#pragma unroll
      for (int t = 0; t < 6; ++t) {
        const int head = t >> 1, dim = (t & 1) * 16 + l15;
        *(bf16x4*)&v_s[(head * 32 + dim) * LDV + rowb + 4 * g4] =
            __builtin_convertvector(acc[t], bf16x4);
      }
    }
  }

  __syncthreads();   // barrier #1: k_s/v_s visible; h region dead (P reuse ok)

  // ---------------- Phase 3: attention, swapped QK^T, head by head ----------
  // Lane (g4,l15) of wave wv handles q = rowb+l15, toks {16n + 4g4 + r}.
  const float* bvar = biasf + (((wy == 15) * 2 + (wx == 15)) * 3) * 4096;
  const f32x4 zf = {0.f, 0.f, 0.f, 0.f};
  f32x4 ovA[3][2];
#pragma unroll
  for (int h = 0; h < 3; ++h) {
    const float* bh = bvar + h * 4096;
    f32x4 bv[4];
#pragma unroll
    for (int n = 0; n < 4; ++n)
      bv[n] = *(const f32x4*)&bh[(rowb + l15) * 64 + n * 16 + 4 * g4];

    f32x4 sc[4];
#pragma unroll
    for (int n = 0; n < 4; ++n) {
      bf16x8 bk = *(const bf16x8*)&k_s[(n * 16 + l15) * LDA + h * 32 + 8 * g4];
      // swapped: D[ktok][q]; lane col = q = rowb+l15, rows = ktok n*16+4g4+r
      sc[n] = __builtin_amdgcn_mfma_f32_16x16x32_bf16(bk, aq3[h], zf, 0, 0, 0);
    }
    // p = exp2(s + bias) (no max-sub: |logits| small; masked -> exp2(-144)=0)
    float sum = 0.f;
#pragma unroll
    for (int n = 0; n < 4; ++n)
#pragma unroll
      for (int r = 0; r < 4; ++r) {
        const float p = __builtin_amdgcn_exp2f(sc[n][r] + bv[n][r]);
        sc[n][r] = p; sum += p;
      }
    sum += __shfl_xor(sum, 16); sum += __shfl_xor(sum, 32);   // across g4 groups
    const float rs = __builtin_amdgcn_rcpf(sum);
    // normalized P -> h_s rows q=rowb+l15 (dead h; wave-local), bf16x4 stores
#pragma unroll
    for (int n = 0; n < 4; ++n) {
      f32x4 pn;
#pragma unroll
      for (int r = 0; r < 4; ++r) pn[r] = sc[n][r] * rs;
      *(bf16x4*)&h_s[(rowb + l15) * LDA + n * 16 + 4 * g4] =
          __builtin_convertvector(pn, bf16x4);
    }
    f32x4 ov[2] = {zf, zf};
#pragma unroll
    for (int ks = 0; ks < 2; ++ks) {
      bf16x8 pa = *(const bf16x8*)&h_s[(rowb + l15) * LDA + ks * 32 + 8 * g4];
#pragma unroll
      for (int t2 = 0; t2 < 2; ++t2) {
        bf16x8 vb2 = *(const bf16x8*)&v_s[(h * 32 + t2 * 16 + l15) * LDV + ks * 32 + 8 * g4];
        ov[t2] = __builtin_amdgcn_mfma_f32_16x16x32_bf16(pa, vb2, ov[t2], 0, 0, 0);
      }
    }
#pragma unroll
    for (int t2 = 0; t2 < 2; ++t2)
#pragma unroll
      for (int r = 0; r < 4; ++r)
        ovA[h][t2][r] = ov[t2][r];          // P pre-normalized; no rescale
  }
  // flush attn-out to h_s (overwrites dead P; wave-local rows)
#pragma unroll
  for (int h = 0; h < 3; ++h)
#pragma unroll
    for (int t2 = 0; t2 < 2; ++t2)
#pragma unroll
      for (int r = 0; r < 4; ++r)
        h_s[(rowb + 4 * g4 + r) * LDA + h * 32 + t2 * 16 + l15] = (__bf16)ovA[h][t2][r];
  // no barrier: proj reads only own-wave rows

  // ---------------- Phase 4: output projection (B-frags direct) -------------
  f32x4 po[6];
#pragma unroll
  for (int t = 0; t < 6; ++t) po[t] = zf;
#pragma unroll
  for (int ks = 0; ks < 3; ++ks) {
    bf16x8 a = *(const bf16x8*)&h_s[(rowb + l15) * LDA + ks * 32 + 8 * g4];
#pragma unroll
    for (int t = 0; t < 6; ++t) {
      bf16x8 bb = *(const bf16x8*)(fbase + (size_t)(54 + t * 3 + ks) * 512);
      po[t] = __builtin_amdgcn_mfma_f32_16x16x32_bf16(a, bb, po[t], 0, 0, 0);
    }
  }

  // ---------------- Phase 4.5: residual + LN2 fully in registers ------------
  size_t gbase[4];
  float xm[6][4];
#pragma unroll
  for (int r = 0; r < 4; ++r) {
    const int row = rowb + 4 * g4 + r;
    const int ti2 = row >> 3, tj2 = row & 7;
    const int iy = (wy * 8 + ti2 + SHIFT) & 127;
    const int ix = (wx * 8 + tj2 + SHIFT) & 127;
    gbase[r] = ((size_t)(b * 16384 + iy * 128 + ix)) * 96;
#pragma unroll
    for (int t = 0; t < 6; ++t)
      xm[t][r] = x[gbase[r] + t * 16 + l15] + po[t][r];
  }
  {
    float g6[6], b6[6];
#pragma unroll
    for (int t = 0; t < 6; ++t) { g6[t] = ln2g[t * 16 + l15]; b6[t] = ln2b[t * 16 + l15]; }
#pragma unroll
    for (int r = 0; r < 4; ++r) {
      float s = 0.f, ss = 0.f;
#pragma unroll
      for (int t = 0; t < 6; ++t) { s += xm[t][r]; ss += xm[t][r] * xm[t][r]; }
      s  += __shfl_xor(s, 1);  s  += __shfl_xor(s, 2);
      s  += __shfl_xor(s, 4);  s  += __shfl_xor(s, 8);
      ss += __shfl_xor(ss, 1); ss += __shfl_xor(ss, 2);
      ss += __shfl_xor(ss, 4); ss += __shfl_xor(ss, 8);
      const float mean = s * (1.f / 96.f);
      const float var  = ss * (1.f / 96.f) - mean * mean;
      const float rstd = rsqrtf(var + 1e-5f);
#pragma unroll
      for (int t = 0; t < 6; ++t) {
        const float h2 = (xm[t][r] - mean) * rstd * g6[t] + b6[t];
        h_s[(rowb + 4 * g4 + r) * LDA + t * 16 + l15] = (__bf16)h2;
      }
    }
  }

  __syncthreads();   // barrier #2: all k/v reads done -> regions reusable

  // ---------------- Phase 5: MLP, 6 chunks of 64 hidden cols ----------------
  // Per chunk: stage w1c(k-region)+w2c(v-region) in ONE exposure -> bar ->
  // G1 -> bar (w1c reads done) -> gelu->u (over w1c) + G2 -> bar.
  f32x4 acc[6];
#pragma unroll
  for (int t = 0; t < 6; ++t) acc[t] = zf;

  for (int cc = 0; cc < 6; ++cc) {
    {  // stage both chunks (6 pipelined uint4 loads per thread-slot)
      const __bf16* s1 = ws + WS_W1T + cc * 6144;
#pragma unroll
      for (int m = tid; m < 768; m += 256) {
        const int row = m / 12, q4 = m - row * 12;
        *(uint4*)&w1c[row * LDW1 + q4 * 8] = *(const uint4*)&s1[row * 96 + q4 * 8];
      }
      const __bf16* s2 = ws + WS_W2C + cc * 6144;
#pragma unroll
      for (int m = tid; m < 768; m += 256) {
        const int row = m >> 3, q4 = m & 7;
        *(uint4*)&w2c[row * LDW2 + q4 * 8] = *(const uint4*)&s2[row * 64 + q4 * 8];
      }
    }
    __syncthreads();   // staged chunks visible
    f32x4 ua[4];
#pragma unroll
    for (int t = 0; t < 4; ++t) ua[t] = zf;
#pragma unroll
    for (int ks = 0; ks < 3; ++ks) {
      bf16x8 a = *(const bf16x8*)&h_s[(rowb + l15) * LDA + ks * 32 + 8 * g4];
#pragma unroll
      for (int t = 0; t < 4; ++t) {
        bf16x8 bb = *(const bf16x8*)&w1c[(t * 16 + l15) * LDW1 + ks * 32 + 8 * g4];
        ua[t] = __builtin_amdgcn_mfma_f32_16x16x32_bf16(a, bb, ua[t], 0, 0, 0);
      }
    }
    __syncthreads();   // all waves' G1 reads of w1c done -> region reusable as u
    // gelu -> u (own rows, over dead w1c) ; G2 in the same interval
#pragma unroll
    for (int t = 0; t < 4; ++t)
#pragma unroll
      for (int r = 0; r < 4; ++r) {
        const float v = ua[t][r];
        const float e = __builtin_amdgcn_exp2f(2.3022528717f * (v + 0.044715f * v * v * v));
        const float g = v - v * __builtin_amdgcn_rcpf(e + 1.f);
        u_c[(rowb + 4 * g4 + r) * LDU + t * 16 + l15] = (__bf16)g;
      }
#pragma unroll
    for (int ks = 0; ks < 2; ++ks) {
      bf16x8 pa = *(const bf16x8*)&u_c[(rowb + l15) * LDU + ks * 32 + 8 * g4];
#pragma unroll
      for (int t = 0; t < 6; ++t) {
        bf16x8 bb = *(const bf16x8*)&w2c[(t * 16 + l15) * LDW2 + ks * 32 + 8 * g4];
        acc[t] = __builtin_amdgcn_mfma_f32_16x16x32_bf16(pa, bb, acc[t], 0, 0, 0);
      }
    }
    __syncthreads();   // all G2 reads of w2c/u done -> regions restageable
  }

  // ---------------- Epilogue: out = x_mid + mlp ----------------
#pragma unroll
  for (int r = 0; r < 4; ++r)
#pragma unroll
    for (int t = 0; t < 6; ++t)
      out[gbase[r] + t * 16 + l15] = xm[t][r] + acc[t][r];
}

extern "C" void kernel_launch(void* const* d_in, const int* in_sizes, int n_in,
                              void* d_out, int out_size, void* d_ws, size_t ws_size,
                              hipStream_t stream) {
  (void)in_sizes; (void)n_in; (void)out_size; (void)ws_size;
  const float* x     = (const float*)d_in[0];
  const float* ln1g  = (const float*)d_in[1];
  const float* ln1b  = (const float*)d_in[2];
  const float* qkvw  = (const float*)d_in[3];
  const float* qkvb  = (const float*)d_in[4];
  const float* projw = (const float*)d_in[5];
  const float* btab  = (const float*)d_in[6];
  const float* ln2g  = (const float*)d_in[7];
  const float* ln2b  = (const float*)d_in[8];
  const float* w1    = (const float*)d_in[9];
  const float* w2    = (const float*)d_in[10];
  float* out = (float*)d_out;
  __bf16* ws = (__bf16*)d_ws;

  // 159744 items = 110592 weight elems + 49152 bias elems (4 variants)
  swin_prep_kernel<<<624, 256, 0, stream>>>(qkvw, projw, w1, w2, btab, ws);
  swin_block_kernel<<<4096, 256, 0, stream>>>(x, ln1g, ln1b, ws, qkvb, ln2g, ln2b, out);
}